// Round 10
// baseline (158.753 us; speedup 1.0000x reference)
//
#include <hip/hip_runtime.h>
#include <hip/hip_bf16.h>
#include <stdint.h>

// ---------- types ----------
typedef __attribute__((ext_vector_type(8))) __bf16 bf16x8;
typedef __attribute__((ext_vector_type(8))) short short8;
typedef __attribute__((ext_vector_type(4))) float f32x4;

#define C1_QSCALE 0.18033688011112042f   // 0.125 * log2(e), folded into Q

__device__ __forceinline__ unsigned short f2bf(float f) {
    union { float f; unsigned int u; } v; v.f = f;
    unsigned int r = v.u + 0x7fffu + ((v.u >> 16) & 1u);
    return (unsigned short)(r >> 16);
}

__device__ __forceinline__ unsigned int cvtpk(float lo, float hi) {
    unsigned int r;
    asm("v_cvt_pk_bf16_f32 %0, %1, %2" : "=v"(r) : "v"(lo), "v"(hi));
    return r;
}

__device__ __forceinline__ float fexp2(float x) {
    float r;
    asm("v_exp_f32 %0, %1" : "=v"(r) : "v"(x));
    return r;
}

__device__ __forceinline__ void gl_lds16(const void* g, void* l) {
    __builtin_amdgcn_global_load_lds(
        (const __attribute__((address_space(1))) unsigned int*)g,
        (__attribute__((address_space(3))) unsigned int*)l, 16, 0, 0);
}

__device__ __forceinline__ f32x4 mfma16(bf16x8 a, bf16x8 b, f32x4 c) {
    return __builtin_amdgcn_mfma_f32_16x16x32_bf16(a, b, c, 0, 0, 0);
}

// ---------- 1. fused pre-pass: LN (blocks 0..2047) + weight prep (blocks 2048..4095) ----------
__global__ __launch_bounds__(256) void pre_kernel(
    const float* __restrict__ x, const float* __restrict__ lw,
    const float* __restrict__ lb, unsigned short* __restrict__ xn,
    const float* __restrict__ wq, const float* __restrict__ wk,
    const float* __restrict__ wv_v, const float* __restrict__ wv_g,
    const float* __restrict__ w_out,
    unsigned short* __restrict__ wqkv, unsigned short* __restrict__ woutb)
{
    const int t = threadIdx.x;
    if (blockIdx.x < 2048) {
        // ---- LayerNorm, wave-per-row, no barriers ----
        const int wv = t >> 6, l = t & 63;
        const int row = blockIdx.x * 4 + wv;
        const float* xr = x + (size_t)row * 512;
        const float4 a = *(const float4*)(xr + l*8);
        const float4 b = *(const float4*)(xr + l*8 + 4);
        float s  = (a.x + a.y) + (a.z + a.w) + (b.x + b.y) + (b.z + b.w);
        float sq = (a.x*a.x + a.y*a.y) + (a.z*a.z + a.w*a.w)
                 + (b.x*b.x + b.y*b.y) + (b.z*b.z + b.w*b.w);
        #pragma unroll
        for (int m = 1; m < 64; m <<= 1) { s += __shfl_xor(s, m); sq += __shfl_xor(sq, m); }
        const float mean = s * (1.f/512.f);
        const float var  = sq * (1.f/512.f) - mean*mean;
        const float rs   = rsqrtf(var + 1e-5f);
        const float4 w0 = *(const float4*)(lw + l*8);
        const float4 w1 = *(const float4*)(lw + l*8 + 4);
        const float4 c0 = *(const float4*)(lb + l*8);
        const float4 c1 = *(const float4*)(lb + l*8 + 4);
        uint4 o;
        o.x = cvtpk((a.x-mean)*rs*w0.x + c0.x, (a.y-mean)*rs*w0.y + c0.y);
        o.y = cvtpk((a.z-mean)*rs*w0.z + c0.z, (a.w-mean)*rs*w0.w + c0.w);
        o.z = cvtpk((b.x-mean)*rs*w1.x + c1.x, (b.y-mean)*rs*w1.y + c1.y);
        o.w = cvtpk((b.z-mean)*rs*w1.z + c1.z, (b.w-mean)*rs*w1.w + c1.w);
        *(uint4*)(xn + (size_t)row*512 + l*8) = o;
    } else {
        // ---- weight prep ----
        __shared__ float red[4];
        const int row = blockIdx.x - 2048;
        if (row < 1536) {
            const float* src;
            float scale = 1.0f;
            if (row < 512) src = wq + (size_t)row*512;
            else if (row < 1024) src = wk + (size_t)(row-512)*512;
            else {
                src = wv_v + (size_t)(row-1024)*512;
                float2 v = *(const float2*)(src + t*2);
                float sq = v.x*v.x + v.y*v.y;
                #pragma unroll
                for (int m = 1; m < 64; m <<= 1) sq += __shfl_xor(sq, m);
                if ((t & 63) == 0) red[t >> 6] = sq;
                __syncthreads();
                scale = wv_g[row-1024] * rsqrtf(red[0]+red[1]+red[2]+red[3]);
            }
            float2 v = *(const float2*)(src + t*2);
            ushort2 o; o.x = f2bf(v.x*scale); o.y = f2bf(v.y*scale);
            *(ushort2*)(wqkv + (size_t)row*512 + t*2) = o;
        } else {
            const int r = row - 1536;
            float2 v = *(const float2*)(w_out + (size_t)r*512 + t*2);
            ushort2 o; o.x = f2bf(v.x); o.y = f2bf(v.y);
            *(ushort2*)(woutb + (size_t)r*512 + t*2) = o;
        }
    }
}

// ---------- 2/4. NT GEMM: counted-vmcnt single-barrier pipeline, BK=32, 3-deep LDS ----------
template<int MODE, int BM, int BN>
__global__ __launch_bounds__(256) void gemm_nt(
    const unsigned short* __restrict__ A,
    const unsigned short* __restrict__ B,
    unsigned short* __restrict__ qo,
    unsigned short* __restrict__ ko,
    unsigned short* __restrict__ vo,
    float* __restrict__ outf)
{
    constexpr int MT  = BM / 32;          // row 16-tiles per wave
    constexpr int NT  = BN / 32;          // col 16-tiles per wave
    constexpr int ACH = BM / 64;          // A 1KB-chunks per wave per stage
    constexpr int BCH = BN / 64;          // B 1KB-chunks per wave per stage
    constexpr int BUFSZ = (BM + BN) * 64; // bytes per K-step buffer (A then B)
    __shared__ __align__(16) unsigned char L[3][BUFSZ];

    const int t = threadIdx.x;
    const int wv = t >> 6, l = t & 63;
    const int brow = blockIdx.x * BM;
    const int bcol = blockIdx.y * BN;
    const int wr = (wv >> 1) * (BM/2), wc = (wv & 1) * (BN/2);
    const int l15 = l & 15, l4 = l >> 4;
    const int rl  = l >> 2;               // row within 16-row chunk
    const int cbl = l & 3;                // 16B col-block within 64B row

    const f32x4 fz = {0.f, 0.f, 0.f, 0.f};
    f32x4 acc[MT][NT];
    #pragma unroll
    for (int i = 0; i < MT; ++i)
        #pragma unroll
        for (int j = 0; j < NT; ++j) acc[i][j] = fz;

    auto STAGE = [&](int ks, int buf) {
        #pragma unroll
        for (int i = 0; i < ACH; ++i) {
            const int c = wv*ACH + i;
            const int row = c*16 + rl;
            const int scb = cbl ^ ((row >> 1) & 3);
            gl_lds16(A + (size_t)(brow+row)*512 + ks*32 + scb*8, &L[buf][c*1024]);
        }
        #pragma unroll
        for (int i = 0; i < BCH; ++i) {
            const int c = wv*BCH + i;
            const int row = c*16 + rl;
            const int scb = cbl ^ ((row >> 1) & 3);
            gl_lds16(B + (size_t)(bcol+row)*512 + ks*32 + scb*8, &L[buf][BM*64 + c*1024]);
        }
    };

    STAGE(0, 0);
    STAGE(1, 1);

    int cur = 0;
    for (int ks = 0; ks < 16; ++ks) {
        if constexpr (ACH + BCH == 4) asm volatile("s_waitcnt vmcnt(4)" ::: "memory");
        else                          asm volatile("s_waitcnt vmcnt(3)" ::: "memory");
        __builtin_amdgcn_s_barrier();

        int nb = cur + 2; if (nb >= 3) nb -= 3;
        STAGE((ks + 2) & 15, nb);

        bf16x8 af[MT], bfr[NT];
        #pragma unroll
        for (int mt = 0; mt < MT; ++mt) {
            const int row = wr + mt*16 + l15;
            af[mt] = *(const bf16x8*)(&L[cur][0] + row*64 + ((l4 ^ ((row >> 1) & 3))*16));
        }
        #pragma unroll
        for (int nt = 0; nt < NT; ++nt) {
            const int row = wc + nt*16 + l15;
            bfr[nt] = *(const bf16x8*)(&L[cur][BM*64] + row*64 + ((l4 ^ ((row >> 1) & 3))*16));
        }
        __builtin_amdgcn_s_setprio(1);
        #pragma unroll
        for (int mt = 0; mt < MT; ++mt)
            #pragma unroll
            for (int nt = 0; nt < NT; ++nt)
                acc[mt][nt] = mfma16(af[mt], bfr[nt], acc[mt][nt]);
        __builtin_amdgcn_s_setprio(0);

        cur = (cur == 2) ? 0 : cur + 1;
    }

    if (MODE == 1) {
        #pragma unroll
        for (int mt = 0; mt < MT; ++mt)
            #pragma unroll
            for (int nt = 0; nt < NT; ++nt)
                #pragma unroll
                for (int r = 0; r < 4; ++r) {
                    const int grow = brow + wr + mt*16 + l4*4 + r;
                    const int gcol = bcol + wc + nt*16 + l15;
                    outf[(size_t)grow*512 + gcol] = acc[mt][nt][r];
                }
    } else if (bcol < 1024) {
        const bool isq = (bcol < 512);
        unsigned short* dst = isq ? qo : ko;
        const int csub = isq ? bcol : bcol - 512;
        const float scl = isq ? C1_QSCALE : 1.0f;
        #pragma unroll
        for (int mt = 0; mt < MT; ++mt)
            #pragma unroll
            for (int nt = 0; nt < NT; ++nt)
                #pragma unroll
                for (int r = 0; r < 4; ++r) {
                    const int grow = brow + wr + mt*16 + l4*4 + r;
                    const int gcol = csub + wc + nt*16 + l15;
                    const int h = gcol >> 6, d = gcol & 63;
                    const int bb = grow >> 11, n = grow & 2047;
                    dst[(((size_t)bb*8 + h)*2048 + n)*64 + d] = f2bf(acc[mt][nt][r]*scl);
                }
    } else {
        // V section: write transposed [bh][d][n'] with slot permutation
        // sigma(c = mt*16+l4*4+r) = (mt>>1)*32 + l4*8 + (mt&1)*4 + r
        #pragma unroll
        for (int mt = 0; mt < MT; ++mt) {
            const int grow0 = brow + wr + mt*16 + l4*4;
            const int bb = grow0 >> 11;
            const int nb2 = (grow0 & 2047) & ~63;
            const int sigma0 = (mt>>1)*32 + l4*8 + (mt&1)*4;
            #pragma unroll
            for (int nt = 0; nt < NT; ++nt) {
                const int gcol = (bcol - 1024) + wc + nt*16 + l15;
                const int h = gcol >> 6, d = gcol & 63;
                uint2 ov;
                ov.x = cvtpk(acc[mt][nt][0], acc[mt][nt][1]);
                ov.y = cvtpk(acc[mt][nt][2], acc[mt][nt][3]);
                *(uint2*)(vo + ((size_t)(bb*8 + h)*64 + d)*2048 + nb2 + sigma0) = ov;
            }
        }
    }
}

// ---------- 3. flash attention: QBLK=256, 8 waves, 32 q-rows/wave (2 halves share K/V frags) ----------
// Q(pre-scaled),K [bh][n][64], Vt [bh][64][n'(slot-permuted)] -> AO [b][n][512] bf16
// Per-CU LDS read traffic halved vs QBLK=128: one kf/vf fetch feeds two 16-row q-halves.
__global__ __launch_bounds__(512, 2) void flash_attn(
    const unsigned short* __restrict__ Q,
    const unsigned short* __restrict__ K,
    const unsigned short* __restrict__ Vt,
    unsigned short* __restrict__ AO)
{
    __shared__ __align__(16) unsigned char Ks[3][8192];   // 64 keys x 64 d (swizzled)
    __shared__ __align__(16) unsigned char Vs[2][8192];   // 64 d x 64 slots (swizzled)
    const int t = threadIdx.x, wv = t >> 6, l = t & 63;   // wv: 0..7
    const int l15 = l & 15, l4 = l >> 4;
    const int rl = l >> 3, cbl = l & 7;
    const int bh = blockIdx.x;
    const int q0 = blockIdx.y * 256;
    const size_t base = (size_t)bh * 2048 * 64;
    const int b = bh >> 3, h = bh & 7;

    // Q fragments for both 16-row halves (B-operand: col=q=l15, k=8*l4+j)
    bf16x8 qf[2][2];
    #pragma unroll
    for (int hq = 0; hq < 2; ++hq)
        #pragma unroll
        for (int kk = 0; kk < 2; ++kk)
            qf[hq][kk] = *(const bf16x8*)(Q + base + (size_t)(q0 + wv*32 + hq*16 + l15)*64 + kk*32 + 8*l4);

    const f32x4 fz = {0.f,0.f,0.f,0.f};
    f32x4 acco[2][4];       // [hq][dn]
    float lrp[2] = {0.f, 0.f};
    #pragma unroll
    for (int hq = 0; hq < 2; ++hq)
        #pragma unroll
        for (int dn = 0; dn < 4; ++dn) acco[hq][dn] = fz;

    // each wave stages chunk wv (8 rows) of K and V: 1 gl_lds16 each
    auto STAGE_K = [&](int kv, int buf) {
        const int row = wv*8 + rl;
        const int scb = cbl ^ (row & 7);
        gl_lds16(K + base + (size_t)(kv + row)*64 + scb*8, &Ks[buf][wv*1024]);
    };
    auto STAGE_V = [&](int kv, int buf) {
        const int row = wv*8 + rl;
        const int scb = cbl ^ (row & 7);
        gl_lds16(Vt + base + (size_t)row*2048 + kv + scb*8, &Vs[buf][wv*1024]);
    };

    // prologue: 3 ops/wave in flight
    STAGE_V(0, 0);
    STAGE_K(0, 0);
    STAGE_K(64, 1);

    int kb = 0, vb = 0;
    for (int it = 0; it < 32; ++it) {
        asm volatile("s_waitcnt vmcnt(1)" ::: "memory");
        __builtin_amdgcn_s_barrier();

        STAGE_V(((it + 1) & 31) * 64, vb ^ 1);
        STAGE_K(((it + 2) & 31) * 64, kb >= 1 ? kb - 1 : 2);

        // K fragments: loaded ONCE, used by both q-halves
        bf16x8 kf[4][2];
        #pragma unroll
        for (int nt = 0; nt < 4; ++nt)
            #pragma unroll
            for (int kk = 0; kk < 2; ++kk) {
                const int row = nt*16 + l15;
                const int cb = kk*4 + l4;
                kf[nt][kk] = *(const bf16x8*)(&Ks[kb][0] + row*128 + ((cb ^ (row & 7))*16));
            }

        bf16x8 pb[2][2];
        #pragma unroll
        for (int hq = 0; hq < 2; ++hq) {
            f32x4 st[4];
            __builtin_amdgcn_s_setprio(1);
            #pragma unroll
            for (int nt = 0; nt < 4; ++nt) {
                st[nt] = mfma16(kf[nt][0], qf[hq][0], fz);
                st[nt] = mfma16(kf[nt][1], qf[hq][1], st[nt]);
            }
            __builtin_amdgcn_s_setprio(0);

            float p[4][4];
            #pragma unroll
            for (int nt = 0; nt < 4; ++nt)
                #pragma unroll
                for (int r = 0; r < 4; ++r) p[nt][r] = fexp2(st[nt][r]);
            float s0 = (p[0][0]+p[0][1]) + (p[0][2]+p[0][3]);
            float s1 = (p[1][0]+p[1][1]) + (p[1][2]+p[1][3]);
            float s2 = (p[2][0]+p[2][1]) + (p[2][2]+p[2][3]);
            float s3 = (p[3][0]+p[3][1]) + (p[3][2]+p[3][3]);
            lrp[hq] += (s0 + s1) + (s2 + s3);

            #pragma unroll
            for (int kh = 0; kh < 2; ++kh) {
                union { unsigned int u[4]; bf16x8 v; } pu;
                pu.u[0] = cvtpk(p[2*kh][0],   p[2*kh][1]);
                pu.u[1] = cvtpk(p[2*kh][2],   p[2*kh][3]);
                pu.u[2] = cvtpk(p[2*kh+1][0], p[2*kh+1][1]);
                pu.u[3] = cvtpk(p[2*kh+1][2], p[2*kh+1][3]);
                pb[hq][kh] = pu.v;
            }
        }

        // PV: V fragment loaded ONCE per (dn,kh), used by both q-halves
        __builtin_amdgcn_s_setprio(1);
        #pragma unroll
        for (int dn = 0; dn < 4; ++dn)
            #pragma unroll
            for (int kh = 0; kh < 2; ++kh) {
                const int row = dn*16 + l15;
                const int cb = kh*4 + l4;
                const bf16x8 vf = *(const bf16x8*)(&Vs[vb][0] + row*128 + ((cb ^ (row & 7))*16));
                acco[0][dn] = mfma16(vf, pb[0][kh], acco[0][dn]);
                acco[1][dn] = mfma16(vf, pb[1][kh], acco[1][dn]);
            }
        __builtin_amdgcn_s_setprio(0);

        kb = (kb == 2) ? 0 : kb + 1;
        vb ^= 1;
    }

    #pragma unroll
    for (int hq = 0; hq < 2; ++hq) {
        float lr = lrp[hq];
        lr += __shfl_xor(lr, 16);
        lr += __shfl_xor(lr, 32);
        const float inv = 1.f / lr;
        const size_t nrow = (size_t)b*2048 + q0 + wv*32 + hq*16 + l15;
        #pragma unroll
        for (int dn = 0; dn < 4; ++dn) {
            uint2 ov;
            ov.x = cvtpk(acco[hq][dn][0]*inv, acco[hq][dn][1]*inv);
            ov.y = cvtpk(acco[hq][dn][2]*inv, acco[hq][dn][3]*inv);
            *(uint2*)(AO + nrow*512 + h*64 + dn*16 + l4*4) = ov;
        }
    }
}

// ---------- launch ----------
extern "C" void kernel_launch(void* const* d_in, const int* in_sizes, int n_in,
                              void* d_out, int out_size, void* d_ws, size_t ws_size,
                              hipStream_t stream)
{
    const float* x     = (const float*)d_in[0];
    const float* ln_w  = (const float*)d_in[1];
    const float* ln_b  = (const float*)d_in[2];
    const float* wq    = (const float*)d_in[3];
    const float* wk    = (const float*)d_in[4];
    const float* wv_v  = (const float*)d_in[5];
    const float* wv_g  = (const float*)d_in[6];
    const float* w_out = (const float*)d_in[7];
    float* out = (float*)d_out;
    char* ws = (char*)d_ws;

    unsigned short* xn    = (unsigned short*)(ws);             // 8 MB; dead after gemm_qkv
    unsigned short* ao    = (unsigned short*)(ws);             // aliases xn (written by flash)
    unsigned short* wqkv  = (unsigned short*)(ws +  8388608);  // 1.5 MB
    unsigned short* woutb = (unsigned short*)(ws +  9961472);  // 0.5 MB
    unsigned short* q     = (unsigned short*)(ws + 10485760);  // 8 MB
    unsigned short* k     = (unsigned short*)(ws + 18874368);  // 8 MB
    unsigned short* vt    = (unsigned short*)(ws + 27262976);  // 8 MB (written by gemm<0>)
    // total: 35,651,584 bytes

    pre_kernel<<<dim3(4096), dim3(256), 0, stream>>>(x, ln_w, ln_b, xn,
        wq, wk, wv_v, wv_g, w_out, wqkv, woutb);
    gemm_nt<0,128,128><<<dim3(64, 12), dim3(256), 0, stream>>>(xn, wqkv, q, k, vt, (float*)nullptr);
    flash_attn<<<dim3(32, 8), dim3(512), 0, stream>>>(q, k, vt, ao);
    gemm_nt<1,128,64><<<dim3(64, 8), dim3(256), 0, stream>>>(ao, woutb,
        (unsigned short*)nullptr, (unsigned short*)nullptr, (unsigned short*)nullptr, out);
}